// Round 2
// baseline (109.860 us; speedup 1.0000x reference)
//
#include <hip/hip_runtime.h>
#include <hip/hip_bf16.h>

#define NB 4
#define NC 32
#define NH 32
#define NW 32
#define KK 288                   // 32*3*3 patch length
#define PLANE (NB*NC*NH*NW)      // 131072 elements per (y,l,u) plane

// One block per (weight, co) row: zero-mean the 288-long weight row.
__global__ __launch_bounds__(256) void prep_weights_k(
        const float* __restrict__ w1,
        const float* __restrict__ w2,
        float* __restrict__ wf1, float* __restrict__ wf2)
{
    const int row = blockIdx.x;                       // 0..63
    const float* src = (row < NC) ? w1 : w2;
    float* dst = (row < NC) ? wf1 : wf2;
    const int co = row & (NC - 1);
    const int tid = threadIdx.x;
    __shared__ float red[256];
    const float a = (tid < KK)       ? src[co*KK + tid]       : 0.0f;
    const float b = (tid + 256 < KK) ? src[co*KK + tid + 256] : 0.0f;
    red[tid] = a + b;
    __syncthreads();
    for (int s = 128; s > 0; s >>= 1) {
        if (tid < s) red[tid] += red[tid + s];
        __syncthreads();
    }
    const float mean = red[0] * (1.0f / (float)KK);
    if (tid < KK)       dst[co*KK + tid]       = a - mean;
    if (tid + 256 < KK) dst[co*KK + tid + 256] = b - mean;
}

// Norm-dist conv. Block = 32(w) x 8(co). Grid = (h=32, cog=4, b=4).
// STAGE1: reads x/l/u planes, writes fp32 mid planes (relu no-op: all >= 0).
// STAGE2: reads mid planes, adds residual (x/l/u), relu, writes d_out.
template<bool STAGE2>
__global__ __launch_bounds__(256) void normdist_conv_k(
    const float* __restrict__ xb,     // residual planes (also stage-1 input)
    const float* __restrict__ lb,
    const float* __restrict__ ub,
    const float* __restrict__ my,     // stage-2 input planes (mid)
    const float* __restrict__ ml,
    const float* __restrict__ mu,
    const float* __restrict__ wf,
    float* __restrict__ oy, float* __restrict__ ol, float* __restrict__ ou,
    float* __restrict__ out)
{
    const int h   = blockIdx.x;
    const int cog = blockIdx.y;
    const int b   = blockIdx.z;
    const int tx  = threadIdx.x;      // w
    const int ty  = threadIdx.y;      // co within group of 8
    const int tid = ty * 32 + tx;

    // Patch halo: 32 channels x 3 rows x 34 cols (col 0 == gw=-1 pad, col 33 == gw=32 pad)
    __shared__ float sX[NC*3*34];     // 3264 floats
    __shared__ float sL[NC*3*34];
    __shared__ float sU[NC*3*34];
    __shared__ float sW[8*KK];        // 2304 floats

    for (int i = tid; i < 8*KK; i += 256) sW[i] = wf[cog*8*KK + i];

    for (int i = tid; i < NC*3*34; i += 256) {
        const int c   = i / 102;
        const int rem = i - c*102;
        const int r   = rem / 34;
        const int col = rem - r*34;
        const int gh  = h + r - 1;
        const int gw  = col - 1;
        float vx = 0.0f, vl = 0.0f, vu = 0.0f;
        if ((unsigned)gh < NH && (unsigned)gw < NW) {
            const int g = ((b*NC + c)*NH + gh)*NW + gw;
            if (STAGE2) { vx = my[g]; vl = ml[g]; vu = mu[g]; }
            else        { vx = xb[g]; vl = lb[g]; vu = ub[g]; }
        }
        sX[i] = vx; sL[i] = vl; sU[i] = vu;
    }
    __syncthreads();

    float accY = 0.0f, accL = 0.0f, accU = 0.0f;
    const float* wrow = &sW[ty*KK];
    #pragma unroll 2
    for (int c = 0; c < NC; ++c) {
        #pragma unroll
        for (int r = 0; r < 3; ++r) {
            const int pb = (c*3 + r)*34 + tx;   // + kw gives LDS col = gw+1
            const int wb = c*9 + r*3;
            #pragma unroll
            for (int kw = 0; kw < 3; ++kw) {
                const float wv = wrow[wb + kw];
                const float px = sX[pb + kw];
                const float pl = sL[pb + kw];
                const float pu = sU[pb + kw];
                // y: |px-wv|^8 = ((d^2)^2)^2, abs-free
                const float d  = px - wv;
                const float d2 = d*d, d4 = d2*d2;
                accY = fmaf(d4, d4, accY);
                // dl: max(pl-wv, wv-pu, 0)^8
                const float a  = pl - wv;
                const float nb = wv - pu;
                const float m  = fmaxf(fmaxf(a, nb), 0.0f);
                const float m2 = m*m, m4 = m2*m2;
                accL = fmaf(m4, m4, accL);
                // du: max(|pl-wv|,|pu-wv|)^8 = max(a^2,nb^2)^4
                const float a2 = a*a, q2 = nb*nb;
                const float mm2 = fmaxf(a2, q2);
                const float mm4 = mm2*mm2;
                accU = fmaf(mm4, mm4, accU);
            }
        }
    }

    // x^(1/8) = sqrt(sqrt(sqrt(x))); all accs >= 0.
    const float y  = sqrtf(sqrtf(sqrtf(accY)));
    const float dl = sqrtf(sqrtf(sqrtf(accL)));
    const float du = sqrtf(sqrtf(sqrtf(accU)));

    const int co = cog*8 + ty;
    const int o  = ((b*NC + co)*NH + h)*NW + tx;
    if (!STAGE2) {
        oy[o] = y; ol[o] = dl; ou[o] = du;   // relu no-op: all >= 0
    } else {
        out[o]           = fmaxf(y  + xb[o], 0.0f);
        out[PLANE + o]   = fmaxf(dl + lb[o], 0.0f);
        out[2*PLANE + o] = fmaxf(du + ub[o], 0.0f);
    }
}

extern "C" void kernel_launch(void* const* d_in, const int* in_sizes, int n_in,
                              void* d_out, int out_size, void* d_ws, size_t ws_size,
                              hipStream_t stream)
{
    const float* x  = (const float*)d_in[0];
    const float* l  = (const float*)d_in[1];
    const float* u  = (const float*)d_in[2];
    const float* w1 = (const float*)d_in[3];
    const float* w2 = (const float*)d_in[4];
    float* ws  = (float*)d_ws;
    float* wf1 = ws;                      // 9216 floats
    float* wf2 = ws + NC*KK;              // 9216 floats
    float* my  = ws + 2*NC*KK;            // 131072 floats each
    float* ml  = my + PLANE;
    float* mu  = ml + PLANE;
    float* out = (float*)d_out;

    prep_weights_k<<<64, 256, 0, stream>>>(w1, w2, wf1, wf2);

    dim3 blk(32, 8);
    dim3 grd(NH, 4, NB);
    normdist_conv_k<false><<<grd, blk, 0, stream>>>(x, l, u, nullptr, nullptr, nullptr,
                                                    wf1, my, ml, mu, nullptr);
    normdist_conv_k<true ><<<grd, blk, 0, stream>>>(x, l, u, my, ml, mu,
                                                    wf2, nullptr, nullptr, nullptr, out);
}